// Round 1
// 432.994 us; speedup vs baseline: 1.0291x; 1.0291x over previous
//
#include <hip/hip_runtime.h>
#include <hip/hip_bf16.h>
#include <stdint.h>

#define N_NODES 100000
#define N_EDGES 1600000
#define DIM 128
#define N_GRAPHS 128
#define LDA 136   // padded LDS stride in bf16 elems (k_mlp)

#define NBKT 196     // buckets of 512 nodes: bucket = dst >> 9
#define BCAP 12288   // per-bucket temp capacity (mean 8163, sigma ~90)
#define BP   10240   // per-bucket padded colx capacity (mult of 4; max padded ~10061)

typedef unsigned int uint32;
typedef unsigned short ushort16;

typedef __bf16 bf16x8 __attribute__((ext_vector_type(8)));
typedef float fx4 __attribute__((ext_vector_type(4)));

__device__ __forceinline__ float bfLo(uint32 u){ return __builtin_bit_cast(float, (uint32)(u << 16)); }
__device__ __forceinline__ float bfHi(uint32 u){ return __builtin_bit_cast(float, (uint32)(u & 0xFFFF0000u)); }
__device__ __forceinline__ ushort16 f2bf(float f){
  uint32 u = __builtin_bit_cast(uint32, f);
  u = u + 0x7FFFu + ((u >> 16) & 1u);   // round-to-nearest-even
  return (ushort16)(u >> 16);
}
__device__ __forceinline__ uint32 pack2(float a, float b){
  return (uint32)f2bf(a) | ((uint32)f2bf(b) << 16);
}
__device__ __forceinline__ uint32 addpack(uint32 x, uint32 a){
  return pack2(bfLo(x)+bfLo(a), bfHi(x)+bfHi(a));
}

// ---------- conversion (once per launch); block 6250 zeros the pad row in P and Q ----------
__global__ __launch_bounds__(256) void k_cvt_x(const float* __restrict__ x, ushort16* __restrict__ P,
                                               ushort16* __restrict__ Q){
  if (blockIdx.x == 6250){
    int t = threadIdx.x;
    uint4 z = {0u,0u,0u,0u};
    if (t < 16)                *(uint4*)(P + (size_t)N_NODES*128 + t*8)      = z;
    else if (t < 32)           *(uint4*)(Q + (size_t)N_NODES*128 + (t-16)*8) = z;
    return;
  }
  int idx = (blockIdx.x*256 + threadIdx.x) * 8;   // 6250 blocks * 256 * 8 = 12.8M exactly
  float4 v0 = *(const float4*)(x + idx);
  float4 v1 = *(const float4*)(x + idx + 4);
  uint4 o;
  o.x = pack2(v0.x, v0.y); o.y = pack2(v0.z, v0.w);
  o.z = pack2(v1.x, v1.y); o.w = pack2(v1.z, v1.w);
  *(uint4*)(P + idx) = o;
}

// build Wt[layer][n][k] = W[layer][k][n] in bf16 (so MFMA B-frags are contiguous in k)
__global__ __launch_bounds__(256) void k_cvt_w(const float* __restrict__ W1, const float* __restrict__ W2,
                                               ushort16* __restrict__ WtA, ushort16* __restrict__ WtB){
  int idx = blockIdx.x*256 + threadIdx.x;          // 0..98303
  const float* src = (idx < 49152) ? W1 : W2;
  ushort16*    dst = (idx < 49152) ? WtA : WtB;
  int il = idx % 49152;
  int layer = il >> 14;
  int n = (il >> 7) & 127;
  int k = il & 127;
  dst[layer*16384 + n*128 + k] = f2bf(src[layer*16384 + k*128 + n]);
}

// ---------- CSR build: two-phase LDS counting sort ----------
__global__ __launch_bounds__(512) void k_binA(const int* __restrict__ ei,
                                              int* __restrict__ bucketCursor,
                                              int* __restrict__ temp){
  __shared__ int hist[NBKT];
  __shared__ int base[NBKT];
  __shared__ int gbase[NBKT];
  __shared__ int scanbuf[256];
  __shared__ int sVal[8192];
  __shared__ unsigned short sBkt[8192];
  int t = threadIdx.x;
  int e0 = blockIdx.x * 8192;

  for (int i = t; i < NBKT; i += 512) hist[i] = 0;
  __syncthreads();

  int   myv[16];
  short myb[16];
  short myr[16];
  #pragma unroll
  for (int it = 0; it < 16; ++it){
    int e = e0 + it*512 + t;
    int v = 0; short b = -1; short r = 0;
    if (e < N_EDGES){
      int s = ei[e];
      int d = ei[N_EDGES + e];
      b = (short)(d >> 9);
      v = s | ((d & 511) << 17);
      r = (short)atomicAdd(&hist[b], 1);
    }
    myv[it] = v; myb[it] = b; myr[it] = r;
  }
  __syncthreads();

  if (t < 256) scanbuf[t] = (t < NBKT) ? hist[t] : 0;
  __syncthreads();
  for (int off = 1; off < 256; off <<= 1){
    int x = 0;
    if (t < 256 && t >= off) x = scanbuf[t - off];
    __syncthreads();
    if (t < 256) scanbuf[t] += x;
    __syncthreads();
  }
  if (t < NBKT){
    base[t]  = scanbuf[t] - hist[t];                 // exclusive
    gbase[t] = atomicAdd(&bucketCursor[t], hist[t]); // reserve run
  }
  __syncthreads();

  #pragma unroll
  for (int it = 0; it < 16; ++it){
    if (myb[it] >= 0){
      int p = base[myb[it]] + myr[it];
      sVal[p] = myv[it];
      sBkt[p] = (unsigned short)myb[it];
    }
  }
  __syncthreads();

  int cnt = scanbuf[NBKT - 1];
  for (int p = t; p < cnt; p += 512){
    int b = sBkt[p];
    int g = gbase[b] + (p - base[b]);
    if (g < BCAP) temp[b*BCAP + g] = sVal[p];
  }
}

// Phase B: one block per bucket; build 512-node sub-CSR in LDS with per-node
// padding to multiple-of-4 (pad slots -> zero row N_NODES); coalesced colx write.
__global__ __launch_bounds__(512) void k_binB(const int* __restrict__ temp,
                                              const int* __restrict__ bucketCursor,
                                              int* __restrict__ rowptr,
                                              int* __restrict__ rowlen,
                                              int* __restrict__ colx){
  __shared__ int counts[512];
  __shared__ int sc[512];
  __shared__ int cur[512];
  __shared__ int stage[BCAP];
  __shared__ int sorted[BCAP];
  int b = blockIdx.x, t = threadIdx.x;
  int cnt = min(bucketCursor[b], BCAP);
  int gb  = b * BP;
  const int* src = temp + b*BCAP;

  counts[t] = 0;
  __syncthreads();
  for (int p = t; p < cnt; p += 512){
    int v = src[p];
    stage[p] = v;
    atomicAdd(&counts[v >> 17], 1);
  }
  __syncthreads();

  int len  = counts[t];
  int plen = (len + 3) & ~3;          // padded to multiple of 4
  sc[t] = plen; __syncthreads();
  for (int off = 1; off < 512; off <<= 1){
    int x = (t >= off) ? sc[t - off] : 0; __syncthreads(); sc[t] += x; __syncthreads();
  }
  int excl = sc[t] - plen;
  cur[t] = excl;
  int node = b*512 + t;
  if (node < N_NODES){ rowptr[node] = gb + excl; rowlen[node] = plen; }
  __syncthreads();

  for (int p = t; p < cnt; p += 512){
    int v = stage[p];
    int d = v >> 17;
    int pos = atomicAdd(&cur[d], 1);
    sorted[pos] = v & 0x1FFFF;
  }
  __syncthreads();

  // pad fill: each thread pads its own node (<=3 slots) with the zero row
  for (int k = len; k < plen; ++k) sorted[excl + k] = N_NODES;
  __syncthreads();

  int total = sc[511];
  for (int p = t; p < total; p += 512) colx[gb + p] = sorted[p];
}

// ---------- aggregation v2: one wave per node, register-resident slot table ----------
// lane s holds colx[j+s] (s < plen). Per round rd, lane group g (=lane>>4) handles
// slot 4*rd+g: index distributed via one ds_bpermute; 4 independent dwordx4
// gathers in flight per unrolled iteration; no cndmask chains, no redundant
// colx VMEM. float4 accumulators (v_pk_add_f32).
__global__ __launch_bounds__(256) void k_agg(const ushort16* __restrict__ xb, ushort16* __restrict__ ob,
                                             const int* __restrict__ rowptr, const int* __restrict__ rowlen,
                                             const int* __restrict__ colx){
  int node = (blockIdx.x*256 + threadIdx.x) >> 6;   // 25000 blocks * 4 waves, uniform per wave
  int lane = threadIdx.x & 63;
  int g = lane >> 4, o = lane & 15;
  int j    = __builtin_amdgcn_readfirstlane(rowptr[node]);
  int plen = __builtin_amdgcn_readfirstlane(rowlen[node]);
  const uint32* xw = (const uint32*)xb;

  // slot table: lane s holds colx[j+s]; pad beyond plen (never dereferenced)
  int ci = (lane < plen) ? colx[j + lane] : N_NODES;

  int nk = plen >> 2;                     // 4-slot rounds (plen always mult of 4)
  int nk64 = (plen > 64) ? 16 : nk;       // rounds resident in ci

  fx4 acc0 = (fx4){0.f,0.f,0.f,0.f};
  fx4 acc1 = (fx4){0.f,0.f,0.f,0.f};

#define ACC8(u) do { \
    acc0 += (fx4){ bfLo((u).x), bfHi((u).x), bfLo((u).y), bfHi((u).y) }; \
    acc1 += (fx4){ bfLo((u).z), bfHi((u).z), bfLo((u).w), bfHi((u).w) }; \
  } while(0)
#define GATH(r) (*(const uint4*)(xw + (size_t)(r)*64 + o*4))

  int rd = 0;
  int rdFull = nk64 & ~3;
  for (; rd < rdFull; rd += 4){
    int s = 4*rd + g;
    int r0 = __shfl(ci, s,      64);
    int r1 = __shfl(ci, s + 4,  64);
    int r2 = __shfl(ci, s + 8,  64);
    int r3 = __shfl(ci, s + 12, 64);
    uint4 u0 = GATH(r0);
    uint4 u1 = GATH(r1);
    uint4 u2 = GATH(r2);
    uint4 u3 = GATH(r3);
    ACC8(u0); ACC8(u1); ACC8(u2); ACC8(u3);
  }
  if (rd + 2 <= nk64){
    int s = 4*rd + g;
    int r0 = __shfl(ci, s,     64);
    int r1 = __shfl(ci, s + 4, 64);
    uint4 u0 = GATH(r0);
    uint4 u1 = GATH(r1);
    ACC8(u0); ACC8(u1);
    rd += 2;
  }
  if (rd < nk64){
    int r0 = __shfl(ci, 4*rd + g, 64);
    uint4 u0 = GATH(r0);
    ACC8(u0);
  }

  // ultra-rare tail: degree > 64 (Poisson(16) makes this ~impossible, but be safe)
  if (plen > 64){
    int endp = j + plen;
    for (int p = j + 64; p < endp; p += 4){
      int rr = colx[p + g];
      uint4 u = GATH(rr);
      ACC8(u);
    }
  }
#undef GATH
#undef ACC8

  // reduce over edge-slot groups (lane bits 4,5)
  #pragma unroll
  for (int i = 0; i < 4; ++i){
    acc0[i] += __shfl_xor(acc0[i], 16, 64);
    acc0[i] += __shfl_xor(acc0[i], 32, 64);
    acc1[i] += __shfl_xor(acc1[i], 16, 64);
    acc1[i] += __shfl_xor(acc1[i], 32, 64);
  }

  if (g == 0){
    uint4 r;
    r.x = pack2(acc0[0], acc0[1]); r.y = pack2(acc0[2], acc0[3]);
    r.z = pack2(acc1[0], acc1[1]); r.w = pack2(acc1[2], acc1[3]);
    *(uint4*)(ob + (size_t)node*128 + o*8) = r;
  }
}

// ---------- fused GIN MLP: out = relu((x+agg)@W1 + b1)@W2 + b2, in-place over agg buffer ----------
__global__ __launch_bounds__(256) void k_mlp(const ushort16* __restrict__ xb, ushort16* __restrict__ hb,
                                             const ushort16* __restrict__ Wt1, const float* __restrict__ b1,
                                             const ushort16* __restrict__ Wt2, const float* __restrict__ b2){
  __shared__ __attribute__((aligned(16))) ushort16 sA[64 * LDA];
  __shared__ __attribute__((aligned(16))) ushort16 sW[128 * LDA];
  int t = threadIdx.x;
  int row0 = blockIdx.x * 64;

  int sr = t >> 4;            // 0..15
  int sc = (t & 15) * 8;      // 0,8,...,120

  #pragma unroll
  for (int it = 0; it < 4; ++it){
    int row = it*16 + sr;
    int g = row0 + row;
    uint4 o;
    if (g < N_NODES){
      uint4 xv = *(const uint4*)(xb + g*128 + sc);
      uint4 av = *(const uint4*)(hb + g*128 + sc);
      o.x = addpack(xv.x, av.x); o.y = addpack(xv.y, av.y);
      o.z = addpack(xv.z, av.z); o.w = addpack(xv.w, av.w);
    } else { o.x = o.y = o.z = o.w = 0u; }
    *(uint4*)(sA + row*LDA + sc) = o;
  }
  #pragma unroll
  for (int it = 0; it < 8; ++it){
    int row = it*16 + sr;
    *(uint4*)(sW + row*LDA + sc) = *(const uint4*)(Wt1 + row*128 + sc);
  }
  __syncthreads();

  int wave = t >> 6, l = t & 63, m = l & 15, kg = l >> 4;
  fx4 acc[8];
  #pragma unroll
  for (int nt = 0; nt < 8; ++nt) acc[nt] = (fx4){0.f,0.f,0.f,0.f};

  const ushort16* aBase = sA + (wave*16 + m)*LDA + kg*8;
  const ushort16* bBase = sW + m*LDA + kg*8;

  #pragma unroll
  for (int kt = 0; kt < 4; ++kt){
    bf16x8 av = *(const bf16x8*)(aBase + kt*32);
    #pragma unroll
    for (int nt = 0; nt < 8; ++nt){
      bf16x8 bv = *(const bf16x8*)(bBase + nt*16*LDA + kt*32);
      acc[nt] = __builtin_amdgcn_mfma_f32_16x16x32_bf16(av, bv, acc[nt], 0, 0, 0);
    }
  }
  __syncthreads();

  #pragma unroll
  for (int nt = 0; nt < 8; ++nt){
    float bv = b1[nt*16 + m];
    #pragma unroll
    for (int r = 0; r < 4; ++r){
      float v = acc[nt][r] + bv;
      v = fmaxf(v, 0.f);
      sA[(wave*16 + kg*4 + r)*LDA + nt*16 + m] = f2bf(v);
    }
  }
  #pragma unroll
  for (int it = 0; it < 8; ++it){
    int row = it*16 + sr;
    *(uint4*)(sW + row*LDA + sc) = *(const uint4*)(Wt2 + row*128 + sc);
  }
  __syncthreads();

  #pragma unroll
  for (int nt = 0; nt < 8; ++nt) acc[nt] = (fx4){0.f,0.f,0.f,0.f};

  #pragma unroll
  for (int kt = 0; kt < 4; ++kt){
    bf16x8 av = *(const bf16x8*)(aBase + kt*32);
    #pragma unroll
    for (int nt = 0; nt < 8; ++nt){
      bf16x8 bv = *(const bf16x8*)(bBase + nt*16*LDA + kt*32);
      acc[nt] = __builtin_amdgcn_mfma_f32_16x16x32_bf16(av, bv, acc[nt], 0, 0, 0);
    }
  }

  #pragma unroll
  for (int nt = 0; nt < 8; ++nt){
    float bv = b2[nt*16 + m];
    #pragma unroll
    for (int r = 0; r < 4; ++r){
      int g = row0 + wave*16 + kg*4 + r;
      if (g < N_NODES){
        float v = acc[nt][r] + bv;
        hb[g*128 + nt*16 + m] = f2bf(v);
      }
    }
  }
}

// ---------- sum-pool per graph (batch sorted) ----------
__device__ __forceinline__ int lower_bound_i(const int* __restrict__ a, int n, int key){
  int lo = 0, hi = n;
  while (lo < hi){ int mid = (lo + hi) >> 1; if (a[mid] < key) lo = mid + 1; else hi = mid; }
  return lo;
}

__global__ __launch_bounds__(256) void k_pool(const ushort16* __restrict__ xb, const int* __restrict__ batch,
                                              float* __restrict__ out){
  int g = blockIdx.x >> 2;
  int p = blockIdx.x & 3;
  int start = lower_bound_i(batch, N_NODES, g);
  int end   = lower_bound_i(batch, N_NODES, g + 1);
  int t = threadIdx.x;
  int c = t & 127;
  int h = t >> 7;
  float acc = 0.f;
  for (int r = start + p*2 + h; r < end; r += 8){
    uint32 u = (uint32)xb[r*128 + c];
    acc += __builtin_bit_cast(float, (uint32)(u << 16));
  }
  __shared__ float red[256];
  red[t] = acc; __syncthreads();
  if (t < 128) atomicAdd(&out[g*128 + c], red[t] + red[t + 128]);
}

// ---------- launch ----------
extern "C" void kernel_launch(void* const* d_in, const int* in_sizes, int n_in,
                              void* d_out, int out_size, void* d_ws, size_t ws_size,
                              hipStream_t stream) {
  const float* x   = (const float*)d_in[0];
  const float* W1  = (const float*)d_in[1];
  const float* b1  = (const float*)d_in[2];
  const float* W2  = (const float*)d_in[3];
  const float* b2  = (const float*)d_in[4];
  const int*   ei  = (const int*)d_in[5];
  const int*   bat = (const int*)d_in[6];
  float* out = (float*)d_out;

  char* w = (char*)d_ws;
  auto carve = [&](size_t bytes) -> char* {
    char* p = w; w += (bytes + 255) & ~(size_t)255; return p;
  };
  ushort16* P    = (ushort16*)carve((size_t)(N_NODES+1) * DIM * 2);  // +1: zero pad row
  ushort16* Q    = (ushort16*)carve((size_t)(N_NODES+1) * DIM * 2);
  ushort16* WtA  = (ushort16*)carve(3 * 16384 * 2);
  ushort16* WtB  = (ushort16*)carve(3 * 16384 * 2);
  int* rowptr    = (int*)carve((size_t)N_NODES * 4);
  int* rowlen    = (int*)carve((size_t)N_NODES * 4);
  int* colx      = (int*)carve((size_t)NBKT * BP * 4);   // 8.03 MB, fixed bucket regions
  int* bucketCursor = (int*)carve((NBKT + 1) * 4);
  // temp bucket regions alias Q: only live during CSR build (first 9.63 MB; zero row at 25.6 MB is safe)
  int* temp      = (int*)Q;

  hipMemsetAsync(bucketCursor, 0, (NBKT + 1) * 4, stream);
  hipMemsetAsync(d_out, 0, (size_t)N_GRAPHS * DIM * 4, stream);

  k_cvt_x<<<6251, 256, 0, stream>>>(x, P, Q);
  k_cvt_w<<<384, 256, 0, stream>>>(W1, W2, WtA, WtB);

  k_binA<<<(N_EDGES + 8191)/8192, 512, 0, stream>>>(ei, bucketCursor, temp);
  k_binB<<<NBKT, 512, 0, stream>>>(temp, bucketCursor, rowptr, rowlen, colx);

  const int aggGrid = N_NODES / 4;          // 4 waves/block, 1 node/wave
  const int mlpGrid = (N_NODES + 63) / 64;  // 1563

  // layer 0: x=P, agg->Q, mlp(P,Q)->Q
  k_agg<<<aggGrid, 256, 0, stream>>>(P, Q, rowptr, rowlen, colx);
  k_mlp<<<mlpGrid, 256, 0, stream>>>(P, Q, WtA + 0*16384, b1 + 0*128, WtB + 0*16384, b2 + 0*128);
  // layer 1: x=Q, agg->P, mlp(Q,P)->P
  k_agg<<<aggGrid, 256, 0, stream>>>(Q, P, rowptr, rowlen, colx);
  k_mlp<<<mlpGrid, 256, 0, stream>>>(Q, P, WtA + 1*16384, b1 + 1*128, WtB + 1*16384, b2 + 1*128);
  // layer 2: x=P, agg->Q, mlp(P,Q)->Q
  k_agg<<<aggGrid, 256, 0, stream>>>(P, Q, rowptr, rowlen, colx);
  k_mlp<<<mlpGrid, 256, 0, stream>>>(P, Q, WtA + 2*16384, b1 + 2*128, WtB + 2*16384, b2 + 2*128);

  k_pool<<<N_GRAPHS * 4, 256, 0, stream>>>(Q, bat, out);
}

// Round 2
// 419.105 us; speedup vs baseline: 1.0632x; 1.0331x over previous
//
#include <hip/hip_runtime.h>
#include <hip/hip_bf16.h>
#include <stdint.h>

#define N_NODES 100000
#define N_EDGES 1600000
#define DIM 128
#define N_GRAPHS 128
#define LDA 136   // padded LDS stride in bf16 elems (MFMA phase)

#define NBKT 196     // buckets of 512 nodes: bucket = dst >> 9
#define BCAP 12288   // per-bucket temp capacity (mean 8163, sigma ~90)
#define BP   10240   // per-bucket padded colx capacity (mult of 4; max padded ~10061)
#define IDXCAP 2048  // per-64-node-tile staged colx slots (mean ~1120, +29 sigma)

typedef unsigned int uint32;
typedef unsigned short ushort16;

typedef __bf16 bf16x8 __attribute__((ext_vector_type(8)));
typedef float fx4 __attribute__((ext_vector_type(4)));

__device__ __forceinline__ float bfLo(uint32 u){ return __builtin_bit_cast(float, (uint32)(u << 16)); }
__device__ __forceinline__ float bfHi(uint32 u){ return __builtin_bit_cast(float, (uint32)(u & 0xFFFF0000u)); }
__device__ __forceinline__ ushort16 f2bf(float f){
  uint32 u = __builtin_bit_cast(uint32, f);
  u = u + 0x7FFFu + ((u >> 16) & 1u);   // round-to-nearest-even
  return (ushort16)(u >> 16);
}
__device__ __forceinline__ uint32 pack2(float a, float b){
  return (uint32)f2bf(a) | ((uint32)f2bf(b) << 16);
}

// ---------- conversion (once per launch); block 6250 zeros the pad row in P and Q ----------
__global__ __launch_bounds__(256) void k_cvt_x(const float* __restrict__ x, ushort16* __restrict__ P,
                                               ushort16* __restrict__ Q){
  if (blockIdx.x == 6250){
    int t = threadIdx.x;
    uint4 z = {0u,0u,0u,0u};
    if (t < 16)                *(uint4*)(P + (size_t)N_NODES*128 + t*8)      = z;
    else if (t < 32)           *(uint4*)(Q + (size_t)N_NODES*128 + (t-16)*8) = z;
    return;
  }
  int idx = (blockIdx.x*256 + threadIdx.x) * 8;   // 6250 blocks * 256 * 8 = 12.8M exactly
  float4 v0 = *(const float4*)(x + idx);
  float4 v1 = *(const float4*)(x + idx + 4);
  uint4 o;
  o.x = pack2(v0.x, v0.y); o.y = pack2(v0.z, v0.w);
  o.z = pack2(v1.x, v1.y); o.w = pack2(v1.z, v1.w);
  *(uint4*)(P + idx) = o;
}

// build Wt[layer][n][k] = W[layer][k][n] in bf16 (so MFMA B-frags are contiguous in k)
__global__ __launch_bounds__(256) void k_cvt_w(const float* __restrict__ W1, const float* __restrict__ W2,
                                               ushort16* __restrict__ WtA, ushort16* __restrict__ WtB){
  int idx = blockIdx.x*256 + threadIdx.x;          // 0..98303
  const float* src = (idx < 49152) ? W1 : W2;
  ushort16*    dst = (idx < 49152) ? WtA : WtB;
  int il = idx % 49152;
  int layer = il >> 14;
  int n = (il >> 7) & 127;
  int k = il & 127;
  dst[layer*16384 + n*128 + k] = f2bf(src[layer*16384 + k*128 + n]);
}

// ---------- CSR build: two-phase LDS counting sort ----------
__global__ __launch_bounds__(512) void k_binA(const int* __restrict__ ei,
                                              int* __restrict__ bucketCursor,
                                              int* __restrict__ temp){
  __shared__ int hist[NBKT];
  __shared__ int base[NBKT];
  __shared__ int gbase[NBKT];
  __shared__ int scanbuf[256];
  __shared__ int sVal[8192];
  __shared__ unsigned short sBkt[8192];
  int t = threadIdx.x;
  int e0 = blockIdx.x * 8192;

  for (int i = t; i < NBKT; i += 512) hist[i] = 0;
  __syncthreads();

  int   myv[16];
  short myb[16];
  short myr[16];
  #pragma unroll
  for (int it = 0; it < 16; ++it){
    int e = e0 + it*512 + t;
    int v = 0; short b = -1; short r = 0;
    if (e < N_EDGES){
      int s = ei[e];
      int d = ei[N_EDGES + e];
      b = (short)(d >> 9);
      v = s | ((d & 511) << 17);
      r = (short)atomicAdd(&hist[b], 1);
    }
    myv[it] = v; myb[it] = b; myr[it] = r;
  }
  __syncthreads();

  if (t < 256) scanbuf[t] = (t < NBKT) ? hist[t] : 0;
  __syncthreads();
  for (int off = 1; off < 256; off <<= 1){
    int x = 0;
    if (t < 256 && t >= off) x = scanbuf[t - off];
    __syncthreads();
    if (t < 256) scanbuf[t] += x;
    __syncthreads();
  }
  if (t < NBKT){
    base[t]  = scanbuf[t] - hist[t];                 // exclusive
    gbase[t] = atomicAdd(&bucketCursor[t], hist[t]); // reserve run
  }
  __syncthreads();

  #pragma unroll
  for (int it = 0; it < 16; ++it){
    if (myb[it] >= 0){
      int p = base[myb[it]] + myr[it];
      sVal[p] = myv[it];
      sBkt[p] = (unsigned short)myb[it];
    }
  }
  __syncthreads();

  int cnt = scanbuf[NBKT - 1];
  for (int p = t; p < cnt; p += 512){
    int b = sBkt[p];
    int g = gbase[b] + (p - base[b]);
    if (g < BCAP) temp[b*BCAP + g] = sVal[p];
  }
}

// Phase B: one block per bucket; build 512-node sub-CSR in LDS with per-node
// padding to multiple-of-4 (pad slots -> zero row N_NODES); coalesced colx write.
__global__ __launch_bounds__(512) void k_binB(const int* __restrict__ temp,
                                              const int* __restrict__ bucketCursor,
                                              int* __restrict__ rowptr,
                                              int* __restrict__ rowlen,
                                              int* __restrict__ colx){
  __shared__ int counts[512];
  __shared__ int sc[512];
  __shared__ int cur[512];
  __shared__ int stage[BCAP];
  __shared__ int sorted[BCAP];
  int b = blockIdx.x, t = threadIdx.x;
  int cnt = min(bucketCursor[b], BCAP);
  int gb  = b * BP;
  const int* src = temp + b*BCAP;

  counts[t] = 0;
  __syncthreads();
  for (int p = t; p < cnt; p += 512){
    int v = src[p];
    stage[p] = v;
    atomicAdd(&counts[v >> 17], 1);
  }
  __syncthreads();

  int len  = counts[t];
  int plen = (len + 3) & ~3;          // padded to multiple of 4
  sc[t] = plen; __syncthreads();
  for (int off = 1; off < 512; off <<= 1){
    int x = (t >= off) ? sc[t - off] : 0; __syncthreads(); sc[t] += x; __syncthreads();
  }
  int excl = sc[t] - plen;
  cur[t] = excl;
  int node = b*512 + t;
  if (node < N_NODES){ rowptr[node] = gb + excl; rowlen[node] = plen; }
  __syncthreads();

  for (int p = t; p < cnt; p += 512){
    int v = stage[p];
    int d = v >> 17;
    int pos = atomicAdd(&cur[d], 1);
    sorted[pos] = v & 0x1FFFF;
  }
  __syncthreads();

  // pad fill: each thread pads its own node (<=3 slots) with the zero row
  for (int k = len; k < plen; ++k) sorted[excl + k] = N_NODES;
  __syncthreads();

  int total = sc[511];
  for (int p = t; p < total; p += 512) colx[gb + p] = sorted[p];
}

// ---------- fused GIN layer: aggregate 64 nodes into LDS, then MLP via MFMA ----------
// Block = 64 nodes (tile never crosses a 512-node bucket => colx range contiguous).
// Phase 1: stage tile's colx slots into LDS (aliased over sW); each 16-lane group
// owns one node, 8 independent row-gathers in flight; accumulate fp32; add x row;
// write bf16 row into sA. No global agg round-trip, no cross-group reduce.
// Phase 2: (x+agg)@W1+b1 -> relu -> @W2+b2, identical to the proven k_mlp body.
__global__ __launch_bounds__(256, 3) void k_gin(const ushort16* __restrict__ xb, ushort16* __restrict__ hb,
                                                const ushort16* __restrict__ Wt1, const float* __restrict__ b1,
                                                const ushort16* __restrict__ Wt2, const float* __restrict__ b2,
                                                const int* __restrict__ rowptr, const int* __restrict__ rowlen,
                                                const int* __restrict__ colx){
  __shared__ __attribute__((aligned(16))) ushort16 sA[64 * LDA];
  __shared__ __attribute__((aligned(16))) char sWbuf[128 * LDA * 2];   // 34816 B
  ushort16* sW  = (ushort16*)sWbuf;
  int* sIdx = (int*)sWbuf;                       // [IDXCAP] 8192 B, dead before sW load
  int* sOff = (int*)(sWbuf + IDXCAP*4);          // [64]
  int* sLen = (int*)(sWbuf + IDXCAP*4 + 256);    // [64]

  int t = threadIdx.x;
  int row0 = blockIdx.x * 64;
  int jBase = rowptr[row0];
  int lastV = min(row0 + 63, N_NODES - 1);
  int total = rowptr[lastV] + rowlen[lastV] - jBase;

  if (t < 64){
    int g = row0 + t;
    int off = 0, len = 0;
    if (g < N_NODES){ off = rowptr[g] - jBase; len = rowlen[g]; }
    sOff[t] = off; sLen[t] = len;
  }
  bool fast = (total <= IDXCAP);                 // block-uniform
  if (fast){
    for (int p = t; p < total; p += 256) sIdx[p] = colx[jBase + p];
  }
  __syncthreads();

  int wave = t >> 6, lane = t & 63;
  int g16 = lane >> 4, o = lane & 15;
  const uint32* xw = (const uint32*)xb;

#define GATH(r) (*(const uint4*)(xw + (size_t)(r)*64 + o*4))
#define ACC8(u) do { \
    a0 += (fx4){ bfLo((u).x), bfHi((u).x), bfLo((u).y), bfHi((u).y) }; \
    a1 += (fx4){ bfLo((u).z), bfHi((u).z), bfLo((u).w), bfHi((u).w) }; \
  } while(0)

  for (int q = 0; q < 4; ++q){
    int ln  = wave*16 + q*4 + g16;      // local node 0..63
    int off = sOff[ln];
    int len = sLen[ln];                 // multiple of 4 (0 for pad nodes)
    int gn  = row0 + ln;
    uint4 xv = {0u,0u,0u,0u};
    if (gn < N_NODES) xv = *(const uint4*)(xw + (size_t)gn*64 + o*4);
    fx4 a0 = (fx4){0.f,0.f,0.f,0.f};
    fx4 a1 = (fx4){0.f,0.f,0.f,0.f};

    if (fast){
      int rd = 0;
      for (; rd + 8 <= len; rd += 8){
        int i0 = sIdx[off+rd  ], i1 = sIdx[off+rd+1], i2 = sIdx[off+rd+2], i3 = sIdx[off+rd+3];
        int i4 = sIdx[off+rd+4], i5 = sIdx[off+rd+5], i6 = sIdx[off+rd+6], i7 = sIdx[off+rd+7];
        uint4 u0 = GATH(i0); uint4 u1 = GATH(i1); uint4 u2 = GATH(i2); uint4 u3 = GATH(i3);
        uint4 u4 = GATH(i4); uint4 u5 = GATH(i5); uint4 u6 = GATH(i6); uint4 u7 = GATH(i7);
        ACC8(u0); ACC8(u1); ACC8(u2); ACC8(u3);
        ACC8(u4); ACC8(u5); ACC8(u6); ACC8(u7);
      }
      if (rd < len){                    // exactly 4 remain
        int i0 = sIdx[off+rd], i1 = sIdx[off+rd+1], i2 = sIdx[off+rd+2], i3 = sIdx[off+rd+3];
        uint4 u0 = GATH(i0); uint4 u1 = GATH(i1); uint4 u2 = GATH(i2); uint4 u3 = GATH(i3);
        ACC8(u0); ACC8(u1); ACC8(u2); ACC8(u3);
      }
    } else {                            // ~never: tile overflowed IDXCAP
      for (int rd = 0; rd < len; rd += 4){
        int i0 = colx[jBase+off+rd], i1 = colx[jBase+off+rd+1];
        int i2 = colx[jBase+off+rd+2], i3 = colx[jBase+off+rd+3];
        uint4 u0 = GATH(i0); uint4 u1 = GATH(i1); uint4 u2 = GATH(i2); uint4 u3 = GATH(i3);
        ACC8(u0); ACC8(u1); ACC8(u2); ACC8(u3);
      }
    }

    uint4 r;
    r.x = pack2(a0[0]+bfLo(xv.x), a0[1]+bfHi(xv.x));
    r.y = pack2(a0[2]+bfLo(xv.y), a0[3]+bfHi(xv.y));
    r.z = pack2(a1[0]+bfLo(xv.z), a1[1]+bfHi(xv.z));
    r.w = pack2(a1[2]+bfLo(xv.w), a1[3]+bfHi(xv.w));
    *(uint4*)(sA + ln*LDA + o*8) = r;   // own-wave rows
  }
#undef GATH
#undef ACC8
  __syncthreads();                      // all waves done with sIdx/sOff/sLen

  // ---- phase 2: MLP (proven k_mlp body) ----
  int sr = t >> 4;            // 0..15
  int sc = (t & 15) * 8;      // 0,8,...,120
  #pragma unroll
  for (int it = 0; it < 8; ++it){
    int row = it*16 + sr;
    *(uint4*)(sW + row*LDA + sc) = *(const uint4*)(Wt1 + row*128 + sc);
  }
  __syncthreads();

  int m = lane & 15, kg = lane >> 4;
  fx4 acc[8];
  #pragma unroll
  for (int nt = 0; nt < 8; ++nt) acc[nt] = (fx4){0.f,0.f,0.f,0.f};

  const ushort16* aBase = sA + (wave*16 + m)*LDA + kg*8;
  const ushort16* bBase = sW + m*LDA + kg*8;

  #pragma unroll
  for (int kt = 0; kt < 4; ++kt){
    bf16x8 av = *(const bf16x8*)(aBase + kt*32);
    #pragma unroll
    for (int nt = 0; nt < 8; ++nt){
      bf16x8 bv = *(const bf16x8*)(bBase + nt*16*LDA + kt*32);
      acc[nt] = __builtin_amdgcn_mfma_f32_16x16x32_bf16(av, bv, acc[nt], 0, 0, 0);
    }
  }
  __syncthreads();

  #pragma unroll
  for (int nt = 0; nt < 8; ++nt){
    float bv = b1[nt*16 + m];
    #pragma unroll
    for (int r = 0; r < 4; ++r){
      float v = acc[nt][r] + bv;
      v = fmaxf(v, 0.f);
      sA[(wave*16 + kg*4 + r)*LDA + nt*16 + m] = f2bf(v);   // own-wave rows
    }
  }
  #pragma unroll
  for (int it = 0; it < 8; ++it){
    int row = it*16 + sr;
    *(uint4*)(sW + row*LDA + sc) = *(const uint4*)(Wt2 + row*128 + sc);
  }
  __syncthreads();

  #pragma unroll
  for (int nt = 0; nt < 8; ++nt) acc[nt] = (fx4){0.f,0.f,0.f,0.f};

  #pragma unroll
  for (int kt = 0; kt < 4; ++kt){
    bf16x8 av = *(const bf16x8*)(aBase + kt*32);
    #pragma unroll
    for (int nt = 0; nt < 8; ++nt){
      bf16x8 bv = *(const bf16x8*)(bBase + nt*16*LDA + kt*32);
      acc[nt] = __builtin_amdgcn_mfma_f32_16x16x32_bf16(av, bv, acc[nt], 0, 0, 0);
    }
  }

  #pragma unroll
  for (int nt = 0; nt < 8; ++nt){
    float bv = b2[nt*16 + m];
    #pragma unroll
    for (int r = 0; r < 4; ++r){
      int g = row0 + wave*16 + kg*4 + r;
      if (g < N_NODES){
        float v = acc[nt][r] + bv;
        hb[g*128 + nt*16 + m] = f2bf(v);
      }
    }
  }
}

// ---------- sum-pool per graph (batch sorted) ----------
__device__ __forceinline__ int lower_bound_i(const int* __restrict__ a, int n, int key){
  int lo = 0, hi = n;
  while (lo < hi){ int mid = (lo + hi) >> 1; if (a[mid] < key) lo = mid + 1; else hi = mid; }
  return lo;
}

__global__ __launch_bounds__(256) void k_pool(const ushort16* __restrict__ xb, const int* __restrict__ batch,
                                              float* __restrict__ out){
  int g = blockIdx.x >> 2;
  int p = blockIdx.x & 3;
  int start = lower_bound_i(batch, N_NODES, g);
  int end   = lower_bound_i(batch, N_NODES, g + 1);
  int t = threadIdx.x;
  int c = t & 127;
  int h = t >> 7;
  float acc = 0.f;
  for (int r = start + p*2 + h; r < end; r += 8){
    uint32 u = (uint32)xb[r*128 + c];
    acc += __builtin_bit_cast(float, (uint32)(u << 16));
  }
  __shared__ float red[256];
  red[t] = acc; __syncthreads();
  if (t < 128) atomicAdd(&out[g*128 + c], red[t] + red[t + 128]);
}

// ---------- launch ----------
extern "C" void kernel_launch(void* const* d_in, const int* in_sizes, int n_in,
                              void* d_out, int out_size, void* d_ws, size_t ws_size,
                              hipStream_t stream) {
  const float* x   = (const float*)d_in[0];
  const float* W1  = (const float*)d_in[1];
  const float* b1  = (const float*)d_in[2];
  const float* W2  = (const float*)d_in[3];
  const float* b2  = (const float*)d_in[4];
  const int*   ei  = (const int*)d_in[5];
  const int*   bat = (const int*)d_in[6];
  float* out = (float*)d_out;

  char* w = (char*)d_ws;
  auto carve = [&](size_t bytes) -> char* {
    char* p = w; w += (bytes + 255) & ~(size_t)255; return p;
  };
  ushort16* P    = (ushort16*)carve((size_t)(N_NODES+1) * DIM * 2);  // +1: zero pad row
  ushort16* Q    = (ushort16*)carve((size_t)(N_NODES+1) * DIM * 2);
  ushort16* WtA  = (ushort16*)carve(3 * 16384 * 2);
  ushort16* WtB  = (ushort16*)carve(3 * 16384 * 2);
  int* rowptr    = (int*)carve((size_t)N_NODES * 4);
  int* rowlen    = (int*)carve((size_t)N_NODES * 4);
  int* colx      = (int*)carve((size_t)NBKT * BP * 4);   // 8.03 MB, fixed bucket regions
  int* bucketCursor = (int*)carve((NBKT + 1) * 4);
  // temp bucket regions alias Q: only live during CSR build (first 9.63 MB; zero row at 25.6 MB is safe)
  int* temp      = (int*)Q;

  hipMemsetAsync(bucketCursor, 0, (NBKT + 1) * 4, stream);
  hipMemsetAsync(d_out, 0, (size_t)N_GRAPHS * DIM * 4, stream);

  k_cvt_x<<<6251, 256, 0, stream>>>(x, P, Q);
  k_cvt_w<<<384, 256, 0, stream>>>(W1, W2, WtA, WtB);

  k_binA<<<(N_EDGES + 8191)/8192, 512, 0, stream>>>(ei, bucketCursor, temp);
  k_binB<<<NBKT, 512, 0, stream>>>(temp, bucketCursor, rowptr, rowlen, colx);

  const int ginGrid = (N_NODES + 63) / 64;  // 1563

  // layer 0: x=P -> out Q;  layer 1: x=Q -> out P;  layer 2: x=P -> out Q
  k_gin<<<ginGrid, 256, 0, stream>>>(P, Q, WtA + 0*16384, b1 + 0*128, WtB + 0*16384, b2 + 0*128,
                                     rowptr, rowlen, colx);
  k_gin<<<ginGrid, 256, 0, stream>>>(Q, P, WtA + 1*16384, b1 + 1*128, WtB + 1*16384, b2 + 1*128,
                                     rowptr, rowlen, colx);
  k_gin<<<ginGrid, 256, 0, stream>>>(P, Q, WtA + 2*16384, b1 + 2*128, WtB + 2*16384, b2 + 2*128,
                                     rowptr, rowlen, colx);

  k_pool<<<N_GRAPHS * 4, 256, 0, stream>>>(Q, bat, out);
}

// Round 3
// 372.922 us; speedup vs baseline: 1.1949x; 1.1238x over previous
//
#include <hip/hip_runtime.h>
#include <hip/hip_bf16.h>
#include <stdint.h>

#define N_NODES 100000
#define N_EDGES 1600000
#define DIM 128
#define N_GRAPHS 128
#define LDA 136   // padded LDS stride in bf16 elems (MFMA phase)

#define NBKT 196     // buckets of 512 nodes: bucket = dst >> 9
#define BCAP 12288   // per-bucket temp capacity (mean 8163, sigma ~90)
#define BP   10240   // per-bucket padded colx capacity (mult of 4; max padded ~10061)
#define IDXCAP 2048  // per-64-node-tile staged colx slots (mean ~1120, +28 sigma)

typedef unsigned int uint32;
typedef unsigned short ushort16;

typedef __bf16 bf16x8 __attribute__((ext_vector_type(8)));
typedef float fx4 __attribute__((ext_vector_type(4)));

__device__ __forceinline__ float bfLo(uint32 u){ return __builtin_bit_cast(float, (uint32)(u << 16)); }
__device__ __forceinline__ float bfHi(uint32 u){ return __builtin_bit_cast(float, (uint32)(u & 0xFFFF0000u)); }
__device__ __forceinline__ ushort16 f2bf(float f){
  uint32 u = __builtin_bit_cast(uint32, f);
  u = u + 0x7FFFu + ((u >> 16) & 1u);   // round-to-nearest-even
  return (ushort16)(u >> 16);
}
__device__ __forceinline__ uint32 pack2(float a, float b){
  return (uint32)f2bf(a) | ((uint32)f2bf(b) << 16);
}

// ---------- conversion (once per launch); block 6250 zeros the pad row in P and Q ----------
__global__ __launch_bounds__(256) void k_cvt_x(const float* __restrict__ x, ushort16* __restrict__ P,
                                               ushort16* __restrict__ Q){
  if (blockIdx.x == 6250){
    int t = threadIdx.x;
    uint4 z = {0u,0u,0u,0u};
    if (t < 16)                *(uint4*)(P + (size_t)N_NODES*128 + t*8)      = z;
    else if (t < 32)           *(uint4*)(Q + (size_t)N_NODES*128 + (t-16)*8) = z;
    return;
  }
  int idx = (blockIdx.x*256 + threadIdx.x) * 8;   // 6250 blocks * 256 * 8 = 12.8M exactly
  float4 v0 = *(const float4*)(x + idx);
  float4 v1 = *(const float4*)(x + idx + 4);
  uint4 o;
  o.x = pack2(v0.x, v0.y); o.y = pack2(v0.z, v0.w);
  o.z = pack2(v1.x, v1.y); o.w = pack2(v1.z, v1.w);
  *(uint4*)(P + idx) = o;
}

// frag-major weight layout: Wf[(layer*2+mat)][nt][kt][lane][8 bf16]
// frag value for lane l: n = nt*16 + (l&15), k = kt*32 + (l>>4)*8 + e  (W[k][n])
// so a wave's B-frag load (per nt,kt) is one fully-coalesced 1KB dwordx4.
__global__ __launch_bounds__(256) void k_cvt_w(const float* __restrict__ W1, const float* __restrict__ W2,
                                               ushort16* __restrict__ Wf){
  int tid = blockIdx.x*256 + threadIdx.x;    // 0..12287
  int layer = tid >> 12;
  int rem   = tid & 4095;
  int mat   = rem >> 11;
  int nt    = (rem >> 8) & 7;
  int kt    = (rem >> 6) & 3;
  int lane  = rem & 63;
  int kg = lane >> 4, m = lane & 15;
  int n  = nt*16 + m;
  int kb = kt*32 + kg*8;
  const float* src = (mat ? W2 : W1) + layer*16384;
  uint4 o;
  o.x = pack2(src[(kb+0)*128 + n], src[(kb+1)*128 + n]);
  o.y = pack2(src[(kb+2)*128 + n], src[(kb+3)*128 + n]);
  o.z = pack2(src[(kb+4)*128 + n], src[(kb+5)*128 + n]);
  o.w = pack2(src[(kb+6)*128 + n], src[(kb+7)*128 + n]);
  *(uint4*)(Wf + ((((size_t)(layer*2+mat)*8 + nt)*4 + kt)*64 + lane)*8) = o;
}

// ---------- CSR build: two-phase LDS counting sort ----------
__global__ __launch_bounds__(512) void k_binA(const int* __restrict__ ei,
                                              int* __restrict__ bucketCursor,
                                              int* __restrict__ temp){
  __shared__ int hist[NBKT];
  __shared__ int base[NBKT];
  __shared__ int gbase[NBKT];
  __shared__ int scanbuf[256];
  __shared__ int sVal[8192];
  __shared__ unsigned short sBkt[8192];
  int t = threadIdx.x;
  int e0 = blockIdx.x * 8192;

  for (int i = t; i < NBKT; i += 512) hist[i] = 0;
  __syncthreads();

  int   myv[16];
  short myb[16];
  short myr[16];
  #pragma unroll
  for (int it = 0; it < 16; ++it){
    int e = e0 + it*512 + t;
    int v = 0; short b = -1; short r = 0;
    if (e < N_EDGES){
      int s = ei[e];
      int d = ei[N_EDGES + e];
      b = (short)(d >> 9);
      v = s | ((d & 511) << 17);
      r = (short)atomicAdd(&hist[b], 1);
    }
    myv[it] = v; myb[it] = b; myr[it] = r;
  }
  __syncthreads();

  if (t < 256) scanbuf[t] = (t < NBKT) ? hist[t] : 0;
  __syncthreads();
  for (int off = 1; off < 256; off <<= 1){
    int x = 0;
    if (t < 256 && t >= off) x = scanbuf[t - off];
    __syncthreads();
    if (t < 256) scanbuf[t] += x;
    __syncthreads();
  }
  if (t < NBKT){
    base[t]  = scanbuf[t] - hist[t];                 // exclusive
    gbase[t] = atomicAdd(&bucketCursor[t], hist[t]); // reserve run
  }
  __syncthreads();

  #pragma unroll
  for (int it = 0; it < 16; ++it){
    if (myb[it] >= 0){
      int p = base[myb[it]] + myr[it];
      sVal[p] = myv[it];
      sBkt[p] = (unsigned short)myb[it];
    }
  }
  __syncthreads();

  int cnt = scanbuf[NBKT - 1];
  for (int p = t; p < cnt; p += 512){
    int b = sBkt[p];
    int g = gbase[b] + (p - base[b]);
    if (g < BCAP) temp[b*BCAP + g] = sVal[p];
  }
}

// Phase B: one block per bucket; build 512-node sub-CSR in LDS with per-node
// padding to multiple-of-4 (pad slots -> zero row N_NODES); coalesced colx write.
__global__ __launch_bounds__(512) void k_binB(const int* __restrict__ temp,
                                              const int* __restrict__ bucketCursor,
                                              int* __restrict__ rowptr,
                                              int* __restrict__ rowlen,
                                              int* __restrict__ colx){
  __shared__ int counts[512];
  __shared__ int sc[512];
  __shared__ int cur[512];
  __shared__ int stage[BCAP];
  __shared__ int sorted[BCAP];
  int b = blockIdx.x, t = threadIdx.x;
  int cnt = min(bucketCursor[b], BCAP);
  int gb  = b * BP;
  const int* src = temp + b*BCAP;

  counts[t] = 0;
  __syncthreads();
  for (int p = t; p < cnt; p += 512){
    int v = src[p];
    stage[p] = v;
    atomicAdd(&counts[v >> 17], 1);
  }
  __syncthreads();

  int len  = counts[t];
  int plen = (len + 3) & ~3;          // padded to multiple of 4
  sc[t] = plen; __syncthreads();
  for (int off = 1; off < 512; off <<= 1){
    int x = (t >= off) ? sc[t - off] : 0; __syncthreads(); sc[t] += x; __syncthreads();
  }
  int excl = sc[t] - plen;
  cur[t] = excl;
  int node = b*512 + t;
  if (node < N_NODES){ rowptr[node] = gb + excl; rowlen[node] = plen; }
  __syncthreads();

  for (int p = t; p < cnt; p += 512){
    int v = stage[p];
    int d = v >> 17;
    int pos = atomicAdd(&cur[d], 1);
    sorted[pos] = v & 0x1FFFF;
  }
  __syncthreads();

  // pad fill: each thread pads its own node (<=3 slots) with the zero row
  for (int k = len; k < plen; ++k) sorted[excl + k] = N_NODES;
  __syncthreads();

  int total = sc[511];
  for (int p = t; p < total; p += 512) colx[gb + p] = sorted[p];
}

// ---------- fused GIN layer v2: aggregate 64 nodes into LDS, MLP with reg-resident B ----------
// LDS = sA (17.4K) + sIdx (8.2K) + off/len -> 26.1 KB => 6 blocks/CU (24 waves).
// Phase 2: wave w owns output cols [32w,32w+32); B-frags live in 32 VGPRs, loaded
// coalesced from frag-major Wf. No sW. Barriers fence the in-place h write in sA.
__global__ __launch_bounds__(256, 6) void k_gin(const ushort16* __restrict__ xb, ushort16* __restrict__ hb,
                                                const ushort16* __restrict__ Wt1, const float* __restrict__ b1,
                                                const ushort16* __restrict__ Wt2, const float* __restrict__ b2,
                                                const int* __restrict__ rowptr, const int* __restrict__ rowlen,
                                                const int* __restrict__ colx){
  __shared__ __attribute__((aligned(16))) ushort16 sA[64 * LDA];
  __shared__ __attribute__((aligned(16))) int sIdx[IDXCAP];
  __shared__ int sOff[64];
  __shared__ int sLen[64];

  int t = threadIdx.x;
  int row0 = blockIdx.x * 64;
  int jBase = rowptr[row0];
  int lastV = min(row0 + 63, N_NODES - 1);
  int total = rowptr[lastV] + rowlen[lastV] - jBase;

  if (t < 64){
    int g = row0 + t;
    int off = 0, len = 0;
    if (g < N_NODES){ off = rowptr[g] - jBase; len = rowlen[g]; }
    sOff[t] = off; sLen[t] = len;
  }
  bool fast = (total <= IDXCAP);                 // block-uniform
  if (fast){
    for (int p = t; p < total; p += 256) sIdx[p] = colx[jBase + p];
  }
  __syncthreads();

  int wave = t >> 6, lane = t & 63;
  int g16 = lane >> 4, o = lane & 15;
  const uint32* xw = (const uint32*)xb;

#define GATH(r) (*(const uint4*)(xw + (size_t)(r)*64 + o*4))
#define ACC8(u) do { \
    a0 += (fx4){ bfLo((u).x), bfHi((u).x), bfLo((u).y), bfHi((u).y) }; \
    a1 += (fx4){ bfLo((u).z), bfHi((u).z), bfLo((u).w), bfHi((u).w) }; \
  } while(0)

  for (int q = 0; q < 4; ++q){
    int ln  = wave*16 + q*4 + g16;      // local node 0..63
    int off = sOff[ln];
    int len = sLen[ln];                 // multiple of 4 (0 for pad nodes)
    int gn  = row0 + ln;
    uint4 xv = {0u,0u,0u,0u};
    if (gn < N_NODES) xv = *(const uint4*)(xw + (size_t)gn*64 + o*4);
    fx4 a0 = (fx4){0.f,0.f,0.f,0.f};
    fx4 a1 = (fx4){0.f,0.f,0.f,0.f};

    if (fast){
      int rd = 0;
      for (; rd + 8 <= len; rd += 8){
        int i0 = sIdx[off+rd  ], i1 = sIdx[off+rd+1], i2 = sIdx[off+rd+2], i3 = sIdx[off+rd+3];
        int i4 = sIdx[off+rd+4], i5 = sIdx[off+rd+5], i6 = sIdx[off+rd+6], i7 = sIdx[off+rd+7];
        uint4 u0 = GATH(i0); uint4 u1 = GATH(i1); uint4 u2 = GATH(i2); uint4 u3 = GATH(i3);
        uint4 u4 = GATH(i4); uint4 u5 = GATH(i5); uint4 u6 = GATH(i6); uint4 u7 = GATH(i7);
        ACC8(u0); ACC8(u1); ACC8(u2); ACC8(u3);
        ACC8(u4); ACC8(u5); ACC8(u6); ACC8(u7);
      }
      if (rd < len){                    // exactly 4 remain
        int i0 = sIdx[off+rd], i1 = sIdx[off+rd+1], i2 = sIdx[off+rd+2], i3 = sIdx[off+rd+3];
        uint4 u0 = GATH(i0); uint4 u1 = GATH(i1); uint4 u2 = GATH(i2); uint4 u3 = GATH(i3);
        ACC8(u0); ACC8(u1); ACC8(u2); ACC8(u3);
      }
    } else {                            // ~never: tile overflowed IDXCAP
      for (int rd = 0; rd < len; rd += 4){
        int i0 = colx[jBase+off+rd], i1 = colx[jBase+off+rd+1];
        int i2 = colx[jBase+off+rd+2], i3 = colx[jBase+off+rd+3];
        uint4 u0 = GATH(i0); uint4 u1 = GATH(i1); uint4 u2 = GATH(i2); uint4 u3 = GATH(i3);
        ACC8(u0); ACC8(u1); ACC8(u2); ACC8(u3);
      }
    }

    uint4 r;
    r.x = pack2(a0[0]+bfLo(xv.x), a0[1]+bfHi(xv.x));
    r.y = pack2(a0[2]+bfLo(xv.y), a0[3]+bfHi(xv.y));
    r.z = pack2(a1[0]+bfLo(xv.z), a1[1]+bfHi(xv.z));
    r.w = pack2(a1[2]+bfLo(xv.w), a1[3]+bfHi(xv.w));
    *(uint4*)(sA + ln*LDA + o*8) = r;   // own-wave rows
  }
#undef GATH
#undef ACC8
  __syncthreads();                      // sA(x+agg) complete

  // ---- phase 2: MLP, wave w owns output cols [32w, 32w+32) ----
  int m = lane & 15, kg = lane >> 4;
  int n0 = wave * 2;                    // nt pair base (nt in [0,8))

  bf16x8 bfa[4], bfb[4];
  #pragma unroll
  for (int kt = 0; kt < 4; ++kt){
    bfa[kt] = *(const bf16x8*)(Wt1 + (((n0+0)*4 + kt)*64 + lane)*8);
    bfb[kt] = *(const bf16x8*)(Wt1 + (((n0+1)*4 + kt)*64 + lane)*8);
  }

  fx4 acc[4][2];
  #pragma unroll
  for (int mt = 0; mt < 4; ++mt){ acc[mt][0] = (fx4){0,0,0,0}; acc[mt][1] = (fx4){0,0,0,0}; }

  #pragma unroll
  for (int kt = 0; kt < 4; ++kt){
    #pragma unroll
    for (int mt = 0; mt < 4; ++mt){
      bf16x8 av = *(const bf16x8*)(sA + (mt*16 + m)*LDA + kg*8 + kt*32);
      acc[mt][0] = __builtin_amdgcn_mfma_f32_16x16x32_bf16(av, bfa[kt], acc[mt][0], 0, 0, 0);
      acc[mt][1] = __builtin_amdgcn_mfma_f32_16x16x32_bf16(av, bfb[kt], acc[mt][1], 0, 0, 0);
    }
  }
  float bva = b1[(n0+0)*16 + m];
  float bvb = b1[(n0+1)*16 + m];
  __syncthreads();                      // all waves done reading sA(x+agg)

  #pragma unroll
  for (int mt = 0; mt < 4; ++mt){
    #pragma unroll
    for (int r = 0; r < 4; ++r){
      int row = mt*16 + kg*4 + r;
      sA[row*LDA + (n0+0)*16 + m] = f2bf(fmaxf(acc[mt][0][r] + bva, 0.f));
      sA[row*LDA + (n0+1)*16 + m] = f2bf(fmaxf(acc[mt][1][r] + bvb, 0.f));
    }
  }
  #pragma unroll
  for (int kt = 0; kt < 4; ++kt){
    bfa[kt] = *(const bf16x8*)(Wt2 + (((n0+0)*4 + kt)*64 + lane)*8);
    bfb[kt] = *(const bf16x8*)(Wt2 + (((n0+1)*4 + kt)*64 + lane)*8);
  }
  float cva = b2[(n0+0)*16 + m];
  float cvb = b2[(n0+1)*16 + m];
  #pragma unroll
  for (int mt = 0; mt < 4; ++mt){ acc[mt][0] = (fx4){0,0,0,0}; acc[mt][1] = (fx4){0,0,0,0}; }
  __syncthreads();                      // h fully written

  #pragma unroll
  for (int kt = 0; kt < 4; ++kt){
    #pragma unroll
    for (int mt = 0; mt < 4; ++mt){
      bf16x8 av = *(const bf16x8*)(sA + (mt*16 + m)*LDA + kg*8 + kt*32);
      acc[mt][0] = __builtin_amdgcn_mfma_f32_16x16x32_bf16(av, bfa[kt], acc[mt][0], 0, 0, 0);
      acc[mt][1] = __builtin_amdgcn_mfma_f32_16x16x32_bf16(av, bfb[kt], acc[mt][1], 0, 0, 0);
    }
  }

  #pragma unroll
  for (int mt = 0; mt < 4; ++mt){
    #pragma unroll
    for (int r = 0; r < 4; ++r){
      int row = row0 + mt*16 + kg*4 + r;
      if (row < N_NODES){
        hb[row*128 + (n0+0)*16 + m] = f2bf(acc[mt][0][r] + cva);
        hb[row*128 + (n0+1)*16 + m] = f2bf(acc[mt][1][r] + cvb);
      }
    }
  }
}

// ---------- sum-pool per graph (batch sorted) ----------
__device__ __forceinline__ int lower_bound_i(const int* __restrict__ a, int n, int key){
  int lo = 0, hi = n;
  while (lo < hi){ int mid = (lo + hi) >> 1; if (a[mid] < key) lo = mid + 1; else hi = mid; }
  return lo;
}

__global__ __launch_bounds__(256) void k_pool(const ushort16* __restrict__ xb, const int* __restrict__ batch,
                                              float* __restrict__ out){
  int g = blockIdx.x >> 2;
  int p = blockIdx.x & 3;
  int start = lower_bound_i(batch, N_NODES, g);
  int end   = lower_bound_i(batch, N_NODES, g + 1);
  int t = threadIdx.x;
  int c = t & 127;
  int h = t >> 7;
  float acc = 0.f;
  for (int r = start + p*2 + h; r < end; r += 8){
    uint32 u = (uint32)xb[r*128 + c];
    acc += __builtin_bit_cast(float, (uint32)(u << 16));
  }
  __shared__ float red[256];
  red[t] = acc; __syncthreads();
  if (t < 128) atomicAdd(&out[g*128 + c], red[t] + red[t + 128]);
}

// ---------- launch ----------
extern "C" void kernel_launch(void* const* d_in, const int* in_sizes, int n_in,
                              void* d_out, int out_size, void* d_ws, size_t ws_size,
                              hipStream_t stream) {
  const float* x   = (const float*)d_in[0];
  const float* W1  = (const float*)d_in[1];
  const float* b1  = (const float*)d_in[2];
  const float* W2  = (const float*)d_in[3];
  const float* b2  = (const float*)d_in[4];
  const int*   ei  = (const int*)d_in[5];
  const int*   bat = (const int*)d_in[6];
  float* out = (float*)d_out;

  char* w = (char*)d_ws;
  auto carve = [&](size_t bytes) -> char* {
    char* p = w; w += (bytes + 255) & ~(size_t)255; return p;
  };
  ushort16* P    = (ushort16*)carve((size_t)(N_NODES+1) * DIM * 2);  // +1: zero pad row
  ushort16* Q    = (ushort16*)carve((size_t)(N_NODES+1) * DIM * 2);
  ushort16* Wf   = (ushort16*)carve((size_t)3 * 2 * 16384 * 2);      // frag-major weights
  int* rowptr    = (int*)carve((size_t)N_NODES * 4);
  int* rowlen    = (int*)carve((size_t)N_NODES * 4);
  int* colx      = (int*)carve((size_t)NBKT * BP * 4);   // 8.03 MB, fixed bucket regions
  int* bucketCursor = (int*)carve((NBKT + 1) * 4);
  // temp bucket regions alias Q: only live during CSR build (first 9.63 MB; zero row at 25.6 MB is safe)
  int* temp      = (int*)Q;

  hipMemsetAsync(bucketCursor, 0, (NBKT + 1) * 4, stream);
  hipMemsetAsync(d_out, 0, (size_t)N_GRAPHS * DIM * 4, stream);

  k_cvt_x<<<6251, 256, 0, stream>>>(x, P, Q);
  k_cvt_w<<<48, 256, 0, stream>>>(W1, W2, Wf);

  k_binA<<<(N_EDGES + 8191)/8192, 512, 0, stream>>>(ei, bucketCursor, temp);
  k_binB<<<NBKT, 512, 0, stream>>>(temp, bucketCursor, rowptr, rowlen, colx);

  const int ginGrid = (N_NODES + 63) / 64;  // 1563

  // layer l: W1-frags at Wf + (l*2+0)*16384, W2-frags at Wf + (l*2+1)*16384
  k_gin<<<ginGrid, 256, 0, stream>>>(P, Q, Wf + 0*16384, b1 + 0*128, Wf + 1*16384, b2 + 0*128,
                                     rowptr, rowlen, colx);
  k_gin<<<ginGrid, 256, 0, stream>>>(Q, P, Wf + 2*16384, b1 + 1*128, Wf + 3*16384, b2 + 1*128,
                                     rowptr, rowlen, colx);
  k_gin<<<ginGrid, 256, 0, stream>>>(P, Q, Wf + 4*16384, b1 + 2*128, Wf + 5*16384, b2 + 2*128,
                                     rowptr, rowlen, colx);

  k_pool<<<N_GRAPHS * 4, 256, 0, stream>>>(Q, bat, out);
}

// Round 4
// 358.901 us; speedup vs baseline: 1.2416x; 1.0391x over previous
//
#include <hip/hip_runtime.h>
#include <hip/hip_bf16.h>
#include <stdint.h>

#define N_NODES 100000
#define N_EDGES 1600000
#define DIM 128
#define N_GRAPHS 128
#define LDA 136   // padded LDS stride in bf16 elems (MFMA phase)

#define NBKT 392     // buckets of 256 nodes: bucket = dst >> 8
#define BCAP 6144    // per-bucket temp capacity (mean 4096, sigma ~64, +32 sigma)
#define BP   5632    // per-bucket padded colx capacity (mult of 4; mean padded 4480 +17 sigma)
#define IDXCAP 2048  // per-64-node-tile staged colx slots (mean ~1120, +28 sigma)

#define NBIN_BLK 391 // ceil(1.6M / 4096) binA blocks inside k_prep
#define CVT_BLK 3125 // 12.8M floats / (512*8)

typedef unsigned int uint32;
typedef unsigned short ushort16;

typedef __bf16 bf16x8 __attribute__((ext_vector_type(8)));
typedef float fx4 __attribute__((ext_vector_type(4)));

__device__ __forceinline__ float bfLo(uint32 u){ return __builtin_bit_cast(float, (uint32)(u << 16)); }
__device__ __forceinline__ float bfHi(uint32 u){ return __builtin_bit_cast(float, (uint32)(u & 0xFFFF0000u)); }
__device__ __forceinline__ ushort16 f2bf(float f){
  uint32 u = __builtin_bit_cast(uint32, f);
  u = u + 0x7FFFu + ((u >> 16) & 1u);   // round-to-nearest-even
  return (ushort16)(u >> 16);
}
__device__ __forceinline__ uint32 pack2(float a, float b){
  return (uint32)f2bf(a) | ((uint32)f2bf(b) << 16);
}

// ---------- fused prep: binA histogram-sort (blocks 0..390) + x->bf16 cvt (391..3515)
//            + pad-row zero (3516) + frag-major W cvt (3517..3540) ----------
// binA blocks co-reside with BW-bound cvt blocks => CSR build hides under cvt HBM time.
__global__ __launch_bounds__(512) void k_prep(const float* __restrict__ x,
                                              const float* __restrict__ W1, const float* __restrict__ W2,
                                              const int* __restrict__ ei,
                                              ushort16* __restrict__ P, ushort16* __restrict__ Q,
                                              ushort16* __restrict__ Wf,
                                              int* __restrict__ bucketCursor,
                                              int* __restrict__ temp){
  __shared__ int hist[NBKT];
  __shared__ int base[NBKT];
  __shared__ int gbase[NBKT];
  __shared__ int scanbuf[512];
  __shared__ int sVal[4096];
  __shared__ unsigned short sBkt[4096];

  int bb = blockIdx.x;
  int t  = threadIdx.x;

  if (bb < NBIN_BLK){
    // ---- binA: bin 4096 edges into per-bucket runs of temp ----
    int e0 = bb * 4096;
    for (int i = t; i < NBKT; i += 512) hist[i] = 0;
    __syncthreads();

    int   myv[8];
    short myb[8];
    short myr[8];
    #pragma unroll
    for (int it = 0; it < 8; ++it){
      int e = e0 + it*512 + t;
      int v = 0; short b = -1; short r = 0;
      if (e < N_EDGES){
        int s = ei[e];
        int d = ei[N_EDGES + e];
        b = (short)(d >> 8);
        v = s | ((d & 255) << 17);
        r = (short)atomicAdd(&hist[b], 1);
      }
      myv[it] = v; myb[it] = b; myr[it] = r;
    }
    __syncthreads();

    scanbuf[t] = (t < NBKT) ? hist[t] : 0;
    __syncthreads();
    for (int off = 1; off < 512; off <<= 1){
      int x2 = 0;
      if (t >= off) x2 = scanbuf[t - off];
      __syncthreads();
      scanbuf[t] += x2;
      __syncthreads();
    }
    if (t < NBKT){
      base[t]  = scanbuf[t] - hist[t];                 // exclusive
      gbase[t] = atomicAdd(&bucketCursor[t], hist[t]); // reserve run
    }
    __syncthreads();

    #pragma unroll
    for (int it = 0; it < 8; ++it){
      if (myb[it] >= 0){
        int p = base[myb[it]] + myr[it];
        sVal[p] = myv[it];
        sBkt[p] = (unsigned short)myb[it];
      }
    }
    __syncthreads();

    int cnt = scanbuf[NBKT - 1];
    for (int p = t; p < cnt; p += 512){
      int b = sBkt[p];
      int g = gbase[b] + (p - base[b]);
      if (g < BCAP) temp[b*BCAP + g] = sVal[p];
    }
    return;
  }

  if (bb < NBIN_BLK + CVT_BLK){
    // ---- cvt_x: 4096 floats per block ----
    int idx = ((bb - NBIN_BLK)*512 + t) * 8;
    float4 v0 = *(const float4*)(x + idx);
    float4 v1 = *(const float4*)(x + idx + 4);
    uint4 o;
    o.x = pack2(v0.x, v0.y); o.y = pack2(v0.z, v0.w);
    o.z = pack2(v1.x, v1.y); o.w = pack2(v1.z, v1.w);
    *(uint4*)(P + idx) = o;
    return;
  }

  if (bb == NBIN_BLK + CVT_BLK){
    // ---- zero the pad row (node N_NODES) in P and Q ----
    uint4 z = {0u,0u,0u,0u};
    if (t < 16)                *(uint4*)(P + (size_t)N_NODES*128 + t*8)      = z;
    else if (t < 32)           *(uint4*)(Q + (size_t)N_NODES*128 + (t-16)*8) = z;
    return;
  }

  // ---- cvt_w: frag-major Wf[(layer*2+mat)][nt][kt][lane][8] ----
  int tid = (bb - (NBIN_BLK + CVT_BLK + 1))*512 + t;   // 0..12287
  int layer = tid >> 12;
  int rem   = tid & 4095;
  int mat   = rem >> 11;
  int nt    = (rem >> 8) & 7;
  int kt    = (rem >> 6) & 3;
  int lane  = rem & 63;
  int kg = lane >> 4, m = lane & 15;
  int n  = nt*16 + m;
  int kb = kt*32 + kg*8;
  const float* src = (mat ? W2 : W1) + layer*16384;
  uint4 o;
  o.x = pack2(src[(kb+0)*128 + n], src[(kb+1)*128 + n]);
  o.y = pack2(src[(kb+2)*128 + n], src[(kb+3)*128 + n]);
  o.z = pack2(src[(kb+4)*128 + n], src[(kb+5)*128 + n]);
  o.w = pack2(src[(kb+6)*128 + n], src[(kb+7)*128 + n]);
  *(uint4*)(Wf + ((((size_t)(layer*2+mat)*8 + nt)*4 + kt)*64 + lane)*8) = o;
}

// ---------- binB: one block per 256-node bucket; build sub-CSR in LDS with per-node
// padding to multiple-of-4 (pad slots -> zero row N_NODES); coalesced colx write. ----------
__global__ __launch_bounds__(512) void k_binB(const int* __restrict__ temp,
                                              const int* __restrict__ bucketCursor,
                                              int* __restrict__ rowptr,
                                              int* __restrict__ rowlen,
                                              int* __restrict__ colx){
  __shared__ int counts[256];
  __shared__ int sc[256];
  __shared__ int cur[256];
  __shared__ int stage[BCAP];
  __shared__ int sorted[BCAP];
  int b = blockIdx.x, t = threadIdx.x;
  int cnt = min(bucketCursor[b], BCAP);
  int gb  = b * BP;
  const int* src = temp + b*BCAP;

  if (t < 256) counts[t] = 0;
  __syncthreads();
  for (int p = t; p < cnt; p += 512){
    int v = src[p];
    stage[p] = v;
    atomicAdd(&counts[v >> 17], 1);
  }
  __syncthreads();

  int len = 0, plen = 0;
  if (t < 256){
    len  = counts[t];
    plen = (len + 3) & ~3;          // padded to multiple of 4
    sc[t] = plen;
  }
  __syncthreads();
  for (int off = 1; off < 256; off <<= 1){
    int x = 0;
    if (t < 256 && t >= off) x = sc[t - off];
    __syncthreads();
    if (t < 256) sc[t] += x;
    __syncthreads();
  }
  int excl = 0;
  if (t < 256){
    excl = sc[t] - plen;
    cur[t] = excl;
    int node = b*256 + t;
    if (node < N_NODES){ rowptr[node] = gb + excl; rowlen[node] = plen; }
  }
  __syncthreads();

  for (int p = t; p < cnt; p += 512){
    int v = stage[p];
    int d = v >> 17;
    int pos = atomicAdd(&cur[d], 1);
    sorted[pos] = v & 0x1FFFF;
  }
  __syncthreads();

  // pad fill: each thread pads its own node (<=3 slots) with the zero row
  if (t < 256){
    for (int k = len; k < plen; ++k) sorted[excl + k] = N_NODES;
  }
  __syncthreads();

  int total = min(sc[255], BP);
  for (int p = t; p < total; p += 512) colx[gb + p] = sorted[p];
}

// ---------- fused GIN layer: aggregate 64 nodes into LDS, MLP with reg-resident B ----------
// LDS = sA (17.4K) + sIdx (8.2K) + off/len -> 26.1 KB => 6 blocks/CU (24 waves).
// Phase 2: wave w owns output cols [32w,32w+32); B-frags live in 32 VGPRs, loaded
// coalesced from frag-major Wf. No sW. Barriers fence the in-place h write in sA.
__global__ __launch_bounds__(256, 6) void k_gin(const ushort16* __restrict__ xb, ushort16* __restrict__ hb,
                                                const ushort16* __restrict__ Wt1, const float* __restrict__ b1,
                                                const ushort16* __restrict__ Wt2, const float* __restrict__ b2,
                                                const int* __restrict__ rowptr, const int* __restrict__ rowlen,
                                                const int* __restrict__ colx){
  __shared__ __attribute__((aligned(16))) ushort16 sA[64 * LDA];
  __shared__ __attribute__((aligned(16))) int sIdx[IDXCAP];
  __shared__ int sOff[64];
  __shared__ int sLen[64];

  int t = threadIdx.x;
  int row0 = blockIdx.x * 64;
  int jBase = rowptr[row0];
  int lastV = min(row0 + 63, N_NODES - 1);
  int total = rowptr[lastV] + rowlen[lastV] - jBase;

  if (t < 64){
    int g = row0 + t;
    int off = 0, len = 0;
    if (g < N_NODES){ off = rowptr[g] - jBase; len = rowlen[g]; }
    sOff[t] = off; sLen[t] = len;
  }
  bool fast = (total <= IDXCAP);                 // block-uniform
  if (fast){
    for (int p = t; p < total; p += 256) sIdx[p] = colx[jBase + p];
  }
  __syncthreads();

  int wave = t >> 6, lane = t & 63;
  int g16 = lane >> 4, o = lane & 15;
  const uint32* xw = (const uint32*)xb;

#define GATH(r) (*(const uint4*)(xw + (size_t)(r)*64 + o*4))
#define ACC8(u) do { \
    a0 += (fx4){ bfLo((u).x), bfHi((u).x), bfLo((u).y), bfHi((u).y) }; \
    a1 += (fx4){ bfLo((u).z), bfHi((u).z), bfLo((u).w), bfHi((u).w) }; \
  } while(0)

  for (int q = 0; q < 4; ++q){
    int ln  = wave*16 + q*4 + g16;      // local node 0..63
    int off = sOff[ln];
    int len = sLen[ln];                 // multiple of 4 (0 for pad nodes)
    int gn  = row0 + ln;
    uint4 xv = {0u,0u,0u,0u};
    if (gn < N_NODES) xv = *(const uint4*)(xw + (size_t)gn*64 + o*4);
    fx4 a0 = (fx4){0.f,0.f,0.f,0.f};
    fx4 a1 = (fx4){0.f,0.f,0.f,0.f};

    if (fast){
      int rd = 0;
      for (; rd + 8 <= len; rd += 8){
        int i0 = sIdx[off+rd  ], i1 = sIdx[off+rd+1], i2 = sIdx[off+rd+2], i3 = sIdx[off+rd+3];
        int i4 = sIdx[off+rd+4], i5 = sIdx[off+rd+5], i6 = sIdx[off+rd+6], i7 = sIdx[off+rd+7];
        uint4 u0 = GATH(i0); uint4 u1 = GATH(i1); uint4 u2 = GATH(i2); uint4 u3 = GATH(i3);
        uint4 u4 = GATH(i4); uint4 u5 = GATH(i5); uint4 u6 = GATH(i6); uint4 u7 = GATH(i7);
        ACC8(u0); ACC8(u1); ACC8(u2); ACC8(u3);
        ACC8(u4); ACC8(u5); ACC8(u6); ACC8(u7);
      }
      if (rd < len){                    // exactly 4 remain
        int i0 = sIdx[off+rd], i1 = sIdx[off+rd+1], i2 = sIdx[off+rd+2], i3 = sIdx[off+rd+3];
        uint4 u0 = GATH(i0); uint4 u1 = GATH(i1); uint4 u2 = GATH(i2); uint4 u3 = GATH(i3);
        ACC8(u0); ACC8(u1); ACC8(u2); ACC8(u3);
      }
    } else {                            // ~never: tile overflowed IDXCAP
      for (int rd = 0; rd < len; rd += 4){
        int i0 = colx[jBase+off+rd], i1 = colx[jBase+off+rd+1];
        int i2 = colx[jBase+off+rd+2], i3 = colx[jBase+off+rd+3];
        uint4 u0 = GATH(i0); uint4 u1 = GATH(i1); uint4 u2 = GATH(i2); uint4 u3 = GATH(i3);
        ACC8(u0); ACC8(u1); ACC8(u2); ACC8(u3);
      }
    }

    uint4 r;
    r.x = pack2(a0[0]+bfLo(xv.x), a0[1]+bfHi(xv.x));
    r.y = pack2(a0[2]+bfLo(xv.y), a0[3]+bfHi(xv.y));
    r.z = pack2(a1[0]+bfLo(xv.z), a1[1]+bfHi(xv.z));
    r.w = pack2(a1[2]+bfLo(xv.w), a1[3]+bfHi(xv.w));
    *(uint4*)(sA + ln*LDA + o*8) = r;   // own-wave rows
  }
#undef GATH
#undef ACC8
  __syncthreads();                      // sA(x+agg) complete

  // ---- phase 2: MLP, wave w owns output cols [32w, 32w+32) ----
  int m = lane & 15, kg = lane >> 4;
  int n0 = wave * 2;                    // nt pair base (nt in [0,8))

  bf16x8 bfa[4], bfb[4];
  #pragma unroll
  for (int kt = 0; kt < 4; ++kt){
    bfa[kt] = *(const bf16x8*)(Wt1 + (((n0+0)*4 + kt)*64 + lane)*8);
    bfb[kt] = *(const bf16x8*)(Wt1 + (((n0+1)*4 + kt)*64 + lane)*8);
  }

  fx4 acc[4][2];
  #pragma unroll
  for (int mt = 0; mt < 4; ++mt){ acc[mt][0] = (fx4){0,0,0,0}; acc[mt][1] = (fx4){0,0,0,0}; }

  #pragma unroll
  for (int kt = 0; kt < 4; ++kt){
    #pragma unroll
    for (int mt = 0; mt < 4; ++mt){
      bf16x8 av = *(const bf16x8*)(sA + (mt*16 + m)*LDA + kg*8 + kt*32);
      acc[mt][0] = __builtin_amdgcn_mfma_f32_16x16x32_bf16(av, bfa[kt], acc[mt][0], 0, 0, 0);
      acc[mt][1] = __builtin_amdgcn_mfma_f32_16x16x32_bf16(av, bfb[kt], acc[mt][1], 0, 0, 0);
    }
  }
  float bva = b1[(n0+0)*16 + m];
  float bvb = b1[(n0+1)*16 + m];
  __syncthreads();                      // all waves done reading sA(x+agg)

  #pragma unroll
  for (int mt = 0; mt < 4; ++mt){
    #pragma unroll
    for (int r = 0; r < 4; ++r){
      int row = mt*16 + kg*4 + r;
      sA[row*LDA + (n0+0)*16 + m] = f2bf(fmaxf(acc[mt][0][r] + bva, 0.f));
      sA[row*LDA + (n0+1)*16 + m] = f2bf(fmaxf(acc[mt][1][r] + bvb, 0.f));
    }
  }
  #pragma unroll
  for (int kt = 0; kt < 4; ++kt){
    bfa[kt] = *(const bf16x8*)(Wt2 + (((n0+0)*4 + kt)*64 + lane)*8);
    bfb[kt] = *(const bf16x8*)(Wt2 + (((n0+1)*4 + kt)*64 + lane)*8);
  }
  float cva = b2[(n0+0)*16 + m];
  float cvb = b2[(n0+1)*16 + m];
  #pragma unroll
  for (int mt = 0; mt < 4; ++mt){ acc[mt][0] = (fx4){0,0,0,0}; acc[mt][1] = (fx4){0,0,0,0}; }
  __syncthreads();                      // h fully written

  #pragma unroll
  for (int kt = 0; kt < 4; ++kt){
    #pragma unroll
    for (int mt = 0; mt < 4; ++mt){
      bf16x8 av = *(const bf16x8*)(sA + (mt*16 + m)*LDA + kg*8 + kt*32);
      acc[mt][0] = __builtin_amdgcn_mfma_f32_16x16x32_bf16(av, bfa[kt], acc[mt][0], 0, 0, 0);
      acc[mt][1] = __builtin_amdgcn_mfma_f32_16x16x32_bf16(av, bfb[kt], acc[mt][1], 0, 0, 0);
    }
  }

  #pragma unroll
  for (int mt = 0; mt < 4; ++mt){
    #pragma unroll
    for (int r = 0; r < 4; ++r){
      int row = row0 + mt*16 + kg*4 + r;
      if (row < N_NODES){
        hb[row*128 + (n0+0)*16 + m] = f2bf(acc[mt][0][r] + cva);
        hb[row*128 + (n0+1)*16 + m] = f2bf(acc[mt][1][r] + cvb);
      }
    }
  }
}

// ---------- sum-pool per graph (batch sorted) ----------
__device__ __forceinline__ int lower_bound_i(const int* __restrict__ a, int n, int key){
  int lo = 0, hi = n;
  while (lo < hi){ int mid = (lo + hi) >> 1; if (a[mid] < key) lo = mid + 1; else hi = mid; }
  return lo;
}

__global__ __launch_bounds__(256) void k_pool(const ushort16* __restrict__ xb, const int* __restrict__ batch,
                                              float* __restrict__ out){
  int g = blockIdx.x >> 2;
  int p = blockIdx.x & 3;
  int start = lower_bound_i(batch, N_NODES, g);
  int end   = lower_bound_i(batch, N_NODES, g + 1);
  int t = threadIdx.x;
  int c = t & 127;
  int h = t >> 7;
  float acc = 0.f;
  for (int r = start + p*2 + h; r < end; r += 8){
    uint32 u = (uint32)xb[r*128 + c];
    acc += __builtin_bit_cast(float, (uint32)(u << 16));
  }
  __shared__ float red[256];
  red[t] = acc; __syncthreads();
  if (t < 128) atomicAdd(&out[g*128 + c], red[t] + red[t + 128]);
}

// ---------- launch ----------
extern "C" void kernel_launch(void* const* d_in, const int* in_sizes, int n_in,
                              void* d_out, int out_size, void* d_ws, size_t ws_size,
                              hipStream_t stream) {
  const float* x   = (const float*)d_in[0];
  const float* W1  = (const float*)d_in[1];
  const float* b1  = (const float*)d_in[2];
  const float* W2  = (const float*)d_in[3];
  const float* b2  = (const float*)d_in[4];
  const int*   ei  = (const int*)d_in[5];
  const int*   bat = (const int*)d_in[6];
  float* out = (float*)d_out;

  char* w = (char*)d_ws;
  auto carve = [&](size_t bytes) -> char* {
    char* p = w; w += (bytes + 255) & ~(size_t)255; return p;
  };
  ushort16* P    = (ushort16*)carve((size_t)(N_NODES+1) * DIM * 2);  // +1: zero pad row
  ushort16* Q    = (ushort16*)carve((size_t)(N_NODES+1) * DIM * 2);
  ushort16* Wf   = (ushort16*)carve((size_t)3 * 2 * 16384 * 2);      // frag-major weights
  int* rowptr    = (int*)carve((size_t)N_NODES * 4);
  int* rowlen    = (int*)carve((size_t)N_NODES * 4);
  int* colx      = (int*)carve((size_t)NBKT * BP * 4);   // 8.83 MB, fixed bucket regions
  int* bucketCursor = (int*)carve((NBKT + 1) * 4);
  // temp bucket regions alias Q: only live during CSR build (first 9.63 MB; Q data
  // written first by gin layer0 after binB; Q pad row at 25.6 MB is beyond temp)
  int* temp      = (int*)Q;

  hipMemsetAsync(bucketCursor, 0, (NBKT + 1) * 4, stream);
  hipMemsetAsync(d_out, 0, (size_t)N_GRAPHS * DIM * 4, stream);

  // fused prep: binA (391) + cvt_x (3125) + pad-zero (1) + cvt_w (24)
  k_prep<<<NBIN_BLK + CVT_BLK + 1 + 24, 512, 0, stream>>>(x, W1, W2, ei, P, Q, Wf,
                                                          bucketCursor, temp);
  k_binB<<<NBKT, 512, 0, stream>>>(temp, bucketCursor, rowptr, rowlen, colx);

  const int ginGrid = (N_NODES + 63) / 64;  // 1563

  // layer l: W1-frags at Wf + (l*2+0)*16384, W2-frags at Wf + (l*2+1)*16384
  k_gin<<<ginGrid, 256, 0, stream>>>(P, Q, Wf + 0*16384, b1 + 0*128, Wf + 1*16384, b2 + 0*128,
                                     rowptr, rowlen, colx);
  k_gin<<<ginGrid, 256, 0, stream>>>(Q, P, Wf + 2*16384, b1 + 1*128, Wf + 3*16384, b2 + 1*128,
                                     rowptr, rowlen, colx);
  k_gin<<<ginGrid, 256, 0, stream>>>(P, Q, Wf + 4*16384, b1 + 2*128, Wf + 5*16384, b2 + 2*128,
                                     rowptr, rowlen, colx);

  k_pool<<<N_GRAPHS * 4, 256, 0, stream>>>(Q, bat, out);
}